// Round 4
// baseline (15.308 us; speedup 1.0000x reference)
//
#include <hip/hip_runtime.h>

// Problem constants (from reference)
#define N_ 16
#define A_ 4096
#define G_ 256
#define C_ 80
#define BIG_ 1e8f
#define LN2_ 0.69314718055994531f

// Structure: block = 256 threads = 4 waves; each wave owns 16 anchors,
// processed in 4 passes of 4 anchors (one per 16-lane group).
// Each lane register-caches 16 gt boxes (interleaved g = sub + 16*m) so the
// hot argmin loop does ZERO LDS traffic. LDS keeps one masked copy of the
// gt boxes/classes for uniform-address (broadcast) epilogue lookups.
// Masked-out boxes are rewritten to (BIG,BIG,BIG,BIG): their distance ~4e8
// never wins; nonempty <=> dmin < BIG; winner is always masked-in.

__global__ __launch_bounds__(256, 4) void cbppl_fused_kernel(
    const float* __restrict__ gt_padded,    // (N, G, 4)
    const float* __restrict__ prop_boxes,   // (N, A, 4)
    const float* __restrict__ pred_boxes,   // (N, A, 4)
    const float* __restrict__ class_logits, // (N, A, C)
    const int*   __restrict__ gt_masks,     // (N, G) bool->int32
    const int*   __restrict__ gt_classes,   // (N, G)
    float* __restrict__ out_cls,            // (N, A)
    float* __restrict__ out_proj)           // (N, A)
{
    __shared__ float4 s_gt[G_];
    __shared__ int    s_cls[G_];

    const int t   = threadIdx.x;
    const int sub = t & 15;                 // lane-in-group
    const int n   = blockIdx.x >> 6;        // 64 blocks per batch
    const int ab  = (blockIdx.x & 63) << 6; // 64 anchors per block

    // ---- one-time: stage masked gt boxes + classes to LDS ----
    {
        const int gidx = n * G_ + t;        // t == g (256 threads)
        float4 g4 = ((const float4*)gt_padded)[gidx];
        if (!gt_masks[gidx]) { g4.x = BIG_; g4.y = BIG_; g4.z = BIG_; g4.w = BIG_; }
        s_gt[t]  = g4;
        s_cls[t] = gt_classes[gidx];
    }
    __syncthreads();

    // ---- one-time: register-cache 16 boxes per lane (interleaved) ----
    // g = sub + 16*m  -> per wave-op, 2-way bank aliasing (free), 4-way bcast
    float4 b[16];
    #pragma unroll
    for (int m = 0; m < 16; ++m) b[m] = s_gt[sub + (m << 4)];

    // ---- 4 passes: 4 anchors per pass (one per 16-lane group) ----
    for (int p = 0; p < 4; ++p) {
        const int ai  = ((t >> 6) << 4) + (p << 2) + ((t >> 4) & 3);
        const int row = n * A_ + ab + ai;

        const float4 pb = ((const float4*)prop_boxes)[row];
        const float4 qb = ((const float4*)pred_boxes)[row];

        // issue the 5 focal-logit loads early (hide HBM latency under argmin)
        const float* lrow = class_logits + (size_t)row * C_;
        float xv[5];
        #pragma unroll
        for (int k = 0; k < 5; ++k) xv[k] = lrow[sub + (k << 4)];

        // local argmin over this lane's 16 register boxes
        float dloc = INFINITY;
        int   mloc = 0;
        #pragma unroll
        for (int m = 0; m < 16; ++m) {
            const float d = fabsf(pb.x - b[m].x) + fabsf(pb.y - b[m].y)
                          + fabsf(pb.z - b[m].z) + fabsf(pb.w - b[m].w);
            if (d < dloc) { dloc = d; mloc = m; }   // lower m = lower g: first occurrence
        }
        const int iloc = (mloc << 4) + sub;          // g index

        // 16-lane group argmin: min(d) then min(index among bitwise-tied lanes)
        float dmin = dloc;
        #pragma unroll
        for (int k = 1; k < 16; k <<= 1) dmin = fminf(dmin, __shfl_xor(dmin, k, 64));
        int cand = (dloc == dmin) ? iloc : 0x7FFFFFFF;
        #pragma unroll
        for (int k = 1; k < 16; k <<= 1) cand = min(cand, __shfl_xor(cand, k, 64));
        const int closest  = cand;
        const int nonempty = (dmin < BIG_);

        // epilogue lookups: uniform per group -> LDS broadcast
        const float4 cb     = s_gt[closest];
        const int    target = s_cls[closest];
        const float  pd = fabsf(qb.x - cb.x) + fabsf(qb.y - cb.y)
                        + fabsf(qb.z - cb.z) + fabsf(qb.w - cb.w);

        // focal loss, negative-class closed form:
        //   loss_neg = 0.75 * softplus(x) * p^2,  p = sigmoid(x)
        float acc = 0.0f;
        #pragma unroll
        for (int k = 0; k < 5; ++k) {
            const float x  = xv[k];
            const float e  = __expf(-fabsf(x));
            const float tt = 1.0f + e;
            const float sp = fmaf(LN2_, __log2f(tt), fmaxf(x, 0.0f)); // softplus(x)
            const float r  = __builtin_amdgcn_rcpf(tt);
            const float pp = (x >= 0.0f) ? r : e * r;                 // sigmoid(x)
            acc += sp * pp * pp;
        }
        acc *= 0.75f;

        // single target-class correction (owner lane: (target & 15) == sub)
        {
            const float xt = lrow[target];          // uniform per group
            const float e  = __expf(-fabsf(xt));
            const float tt = 1.0f + e;
            const float sp = fmaf(LN2_, __log2f(tt), fmaxf(xt, 0.0f));
            const float r  = __builtin_amdgcn_rcpf(tt);
            const float pp = (xt >= 0.0f) ? r : e * r;
            const float q  = 1.0f - pp;
            const float corr = 0.25f * (sp - xt) * q * q - 0.75f * sp * pp * pp;
            if ((target & 15) == sub) acc += corr;
        }

        // group sum of focal partials
        #pragma unroll
        for (int k = 1; k < 16; k <<= 1) acc += __shfl_xor(acc, k, 64);

        if (sub == 0) {
            out_cls[row]  = nonempty ? acc * (1.0f / (float)C_) : 0.0f;
            out_proj[row] = nonempty ? pd : 0.0f;
        }
    }
}

extern "C" void kernel_launch(void* const* d_in, const int* in_sizes, int n_in,
                              void* d_out, int out_size, void* d_ws, size_t ws_size,
                              hipStream_t stream) {
    const float* gt_padded    = (const float*)d_in[0];
    const float* prop_boxes   = (const float*)d_in[1];
    const float* pred_boxes   = (const float*)d_in[2];
    const float* class_logits = (const float*)d_in[3];
    const int*   gt_masks     = (const int*)d_in[4];
    const int*   gt_classes   = (const int*)d_in[5];

    float* out = (float*)d_out;
    float* out_cls  = out;             // classification_loss, (N, A)
    float* out_proj = out + N_ * A_;   // projection_loss,     (N, A)

    dim3 grid(N_ * A_ / 64);           // 1024 blocks, 64 anchors each
    dim3 block(256);
    cbppl_fused_kernel<<<grid, block, 0, stream>>>(
        gt_padded, prop_boxes, pred_boxes, class_logits,
        gt_masks, gt_classes, out_cls, out_proj);
}